// Round 15
// baseline (162.872 us; speedup 1.0000x reference)
//
#include <hip/hip_runtime.h>
#include <cstdint>
#include <cstddef>

typedef unsigned short u16;
typedef unsigned char  u8;
typedef __attribute__((ext_vector_type(8))) short short8;
typedef __attribute__((ext_vector_type(4))) float f32x4;
typedef __attribute__((ext_vector_type(2))) float f32x2;
typedef __attribute__((ext_vector_type(4))) unsigned int u32x4;
typedef __attribute__((ext_vector_type(2))) unsigned int u32x2;

#define GLOBAL_AS(p) ((const __attribute__((address_space(1))) void*)(p))
#define LDS_AS(p)    ((__attribute__((address_space(3))) void*)(p))
typedef __attribute__((address_space(3))) const void* lds_cp;

// HW fp8 converters (OCP e4m3 on gfx950), software fallback kept consistent.
#if defined(__has_builtin)
# if __has_builtin(__builtin_amdgcn_cvt_pk_f32_fp8) && __has_builtin(__builtin_amdgcn_cvt_pk_fp8_f32)
#  define HW_FP8 1
# endif
#endif

__device__ __forceinline__ float bf2f(u16 u){
  union { uint32_t u; float f; } c; c.u = ((uint32_t)u) << 16; return c.f;
}
__device__ __forceinline__ u16 f2bf(float f){
  union { float f; uint32_t u; } c; c.f = f;
  uint32_t r = c.u + 0x7fffu + ((c.u >> 16) & 1u);
  return (u16)(r >> 16);
}

__device__ __forceinline__ u8 f2fp8_sw(float x){
  float cx = fminf(fmaxf(x, -448.f), 448.f);
  union { _Float16 h; unsigned short u; } c;
  c.h = (_Float16)(cx * 0.00390625f);     // 2^-8, RNE
  unsigned short mag = c.u & 0x7fff;
  unsigned r = ((unsigned)mag + 0x3Fu + ((mag >> 7) & 1u)) >> 7;
  if (r > 0x7Eu) r = 0x7Eu;
  return (u8)(r | ((c.u >> 8) & 0x80u));
}
__device__ __forceinline__ float fp8d_sw(uint32_t b){
  union { unsigned short u; _Float16 h; } c;
  c.u = (unsigned short)(((b & 0x7fu) << 7) | ((b & 0x80u) << 8));
  return (float)c.h * 256.f;              // true value
}
__device__ __forceinline__ uint32_t enc4(f32x4 v){
#ifdef HW_FP8
  int p = __builtin_amdgcn_cvt_pk_fp8_f32(v[0], v[1], 0, false);
  p     = __builtin_amdgcn_cvt_pk_fp8_f32(v[2], v[3], p, true);
  return (uint32_t)p;
#else
  return (uint32_t)f2fp8_sw(v[0]) | ((uint32_t)f2fp8_sw(v[1]) << 8)
       | ((uint32_t)f2fp8_sw(v[2]) << 16) | ((uint32_t)f2fp8_sw(v[3]) << 24);
#endif
}
__device__ __forceinline__ void dec8(u32x2 u, float* v){
#ifdef HW_FP8
  f32x2 a = __builtin_amdgcn_cvt_pk_f32_fp8((int)u[0], false);
  f32x2 b = __builtin_amdgcn_cvt_pk_f32_fp8((int)u[0], true);
  f32x2 c = __builtin_amdgcn_cvt_pk_f32_fp8((int)u[1], false);
  f32x2 d = __builtin_amdgcn_cvt_pk_f32_fp8((int)u[1], true);
  v[0]=a[0]; v[1]=a[1]; v[2]=b[0]; v[3]=b[1];
  v[4]=c[0]; v[5]=c[1]; v[6]=d[0]; v[7]=d[1];
#else
  v[0]=fp8d_sw(u[0]      ); v[1]=fp8d_sw(u[0] >>  8);
  v[2]=fp8d_sw(u[0] >> 16); v[3]=fp8d_sw(u[0] >> 24);
  v[4]=fp8d_sw(u[1]      ); v[5]=fp8d_sw(u[1] >>  8);
  v[6]=fp8d_sw(u[1] >> 16); v[7]=fp8d_sw(u[1] >> 24);
#endif
}

// -------- fused LayerNorm v3: wave-per-row, 2-row ILP, grid-stride ---------
// 256 thr = 4 waves; each wave processes rows (ri, ri+nw) per iteration:
// 6 f32x4 loads issued back-to-back, two interleaved shfl-reduce chains
// (hides ds_swizzle latency), then both store groups. Tail: second row's
// pointers clamped, stores guarded. Rows 0..8191 query, 8192..51199 feat.
__global__ __launch_bounds__(256) void ln_all(
    const float* __restrict__ q, const float* __restrict__ f,
    const float* __restrict__ qg, const float* __restrict__ qb,
    const float* __restrict__ fg, const float* __restrict__ fb,
    u16* __restrict__ qout, u16* __restrict__ fout)
{
  const int lane = threadIdx.x & 63;
  const int gw = blockIdx.x * 4 + (threadIdx.x >> 6);
  const int nw = gridDim.x * 4;
  const int c4 = lane * 4;

  for (int ri = gw; ri < 51200; ri += 2*nw) {
    const int rj = ri + nw;
    const bool hasB = (rj < 51200);
    const int rjc = hasB ? rj : 51199;

    const bool aq = ri < 8192;
    const size_t ra = aq ? (size_t)ri : (size_t)(ri - 8192);
    const float* xa = (aq ? q : f) + ra * 768 + c4;
    u16* ya = (aq ? qout : fout) + ra * 768 + c4;
    const float* ga  = aq ? qg : fg;
    const float* bta = aq ? qb : fb;

    const bool bq2 = rjc < 8192;
    const size_t rb = bq2 ? (size_t)rjc : (size_t)(rjc - 8192);
    const float* xb = (bq2 ? q : f) + rb * 768 + c4;
    u16* yb = (bq2 ? qout : fout) + rb * 768 + c4;
    const float* gbp = bq2 ? qg : fg;
    const float* bbp = bq2 ? qb : fb;

    // issue all 6 loads back-to-back (2x bytes in flight)
    const f32x4 a0 = *(const f32x4*)(xa);
    const f32x4 a1 = *(const f32x4*)(xa + 256);
    const f32x4 a2 = *(const f32x4*)(xa + 512);
    const f32x4 b0 = *(const f32x4*)(xb);
    const f32x4 b1 = *(const f32x4*)(xb + 256);
    const f32x4 b2 = *(const f32x4*)(xb + 512);

    float sA = a0[0]+a0[1]+a0[2]+a0[3] + a1[0]+a1[1]+a1[2]+a1[3]
             + a2[0]+a2[1]+a2[2]+a2[3];
    float qA = a0[0]*a0[0]+a0[1]*a0[1]+a0[2]*a0[2]+a0[3]*a0[3]
             + a1[0]*a1[0]+a1[1]*a1[1]+a1[2]*a1[2]+a1[3]*a1[3]
             + a2[0]*a2[0]+a2[1]*a2[1]+a2[2]*a2[2]+a2[3]*a2[3];
    float sB = b0[0]+b0[1]+b0[2]+b0[3] + b1[0]+b1[1]+b1[2]+b1[3]
             + b2[0]+b2[1]+b2[2]+b2[3];
    float qB = b0[0]*b0[0]+b0[1]*b0[1]+b0[2]*b0[2]+b0[3]*b0[3]
             + b1[0]*b1[0]+b1[1]*b1[1]+b1[2]*b1[2]+b1[3]*b1[3]
             + b2[0]*b2[0]+b2[1]*b2[1]+b2[2]*b2[2]+b2[3]*b2[3];
    #pragma unroll
    for (int o=1;o<64;o<<=1){
      sA += __shfl_xor(sA,o); qA += __shfl_xor(qA,o);
      sB += __shfl_xor(sB,o); qB += __shfl_xor(qB,o);
    }
    const float mA = sA * (1.f/768.f);
    const float rA = rsqrtf(qA * (1.f/768.f) - mA*mA + 1e-6f);
    const float mB = sB * (1.f/768.f);
    const float rB = rsqrtf(qB * (1.f/768.f) - mB*mB + 1e-6f);

    #pragma unroll
    for (int r=0;r<3;r++){
      const f32x4 v = (r==0) ? a0 : ((r==1) ? a1 : a2);
      const f32x4 gg = *(const f32x4*)(ga  + r*256 + c4);
      const f32x4 bb = *(const f32x4*)(bta + r*256 + c4);
      u32x2 p;
      p[0] = (uint32_t)f2bf((v[0]-mA)*rA*gg[0] + bb[0])
           | ((uint32_t)f2bf((v[1]-mA)*rA*gg[1] + bb[1]) << 16);
      p[1] = (uint32_t)f2bf((v[2]-mA)*rA*gg[2] + bb[2])
           | ((uint32_t)f2bf((v[3]-mA)*rA*gg[3] + bb[3]) << 16);
      *(u32x2*)(ya + r*256) = p;
    }
    if (hasB) {
      #pragma unroll
      for (int r=0;r<3;r++){
        const f32x4 v = (r==0) ? b0 : ((r==1) ? b1 : b2);
        const f32x4 gg = *(const f32x4*)(gbp + r*256 + c4);
        const f32x4 bb = *(const f32x4*)(bbp + r*256 + c4);
        u32x2 p;
        p[0] = (uint32_t)f2bf((v[0]-mB)*rB*gg[0] + bb[0])
             | ((uint32_t)f2bf((v[1]-mB)*rB*gg[1] + bb[1]) << 16);
        p[1] = (uint32_t)f2bf((v[2]-mB)*rB*gg[2] + bb[2])
             | ((uint32_t)f2bf((v[3]-mB)*rB*gg[3] + bb[3]) << 16);
        *(u32x2*)(yb + r*256) = p;
      }
    }
  }
}

// -------- fused weight prep: all transposes + Wsat tail zero + bsa ---------
__device__ __forceinline__ void tcast_body(const float* __restrict__ in,
    int ld, int ncnt, u16* __restrict__ out, int bx, int by,
    float (*tile)[33])
{
  const int tx = threadIdx.x & 31, ty = threadIdx.x >> 5;
  const int n0 = bx * 32, k0 = by * 32;
  #pragma unroll
  for (int i=0;i<4;i++){
    int k = k0 + ty + 8*i, n = n0 + tx;
    tile[ty+8*i][tx] = (n < ncnt) ? in[(size_t)k*ld + n] : 0.f;
  }
  __syncthreads();
  #pragma unroll
  for (int i=0;i<4;i++){
    int n = n0 + ty + 8*i, k = k0 + tx;
    if (n < ncnt) out[(size_t)n*768 + k] = f2bf(tile[tx][ty+8*i]);
  }
}

__global__ __launch_bounds__(256) void prep_weights(
    const float* __restrict__ Wv, const float* __restrict__ Wo,
    const float* __restrict__ Ws, const float* __restrict__ Wa,
    const float* __restrict__ bs, const float* __restrict__ ba,
    u16* __restrict__ Wvt, u16* __restrict__ Wot,
    u16* __restrict__ Wsat, float* __restrict__ bsa)
{
  __shared__ float tile[32][33];
  const int blk = blockIdx.x;
  if (blk < 576) {
    tcast_body(Wv, 768, 768, Wvt, blk % 24, blk / 24, tile);
  } else if (blk < 1152) {
    const int sub = blk - 576;
    tcast_body(Wo, 768, 768, Wot, sub % 24, sub / 24, tile);
  } else if (blk < 1272) {
    const int sub = blk - 1152;
    tcast_body(Ws, 144, 144, Wsat, sub % 5, sub / 5, tile);
  } else if (blk < 1344) {
    const int sub = blk - 1272;
    tcast_body(Wa, 72, 72, Wsat + (size_t)144*768, sub % 3, sub / 3, tile);
  } else if (blk < 1464) {
    const int sub = blk - 1344;          // zero rows 216..255 of Wsat
    Wsat[(size_t)216*768 + sub*256 + threadIdx.x] = 0;
  } else {
    const int t = threadIdx.x;
    bsa[t] = (t < 144) ? bs[t] : ((t < 216) ? ba[t-144] : 0.f);
  }
}

// ============ 128x128 pipelined MFMA GEMM, 2 blocks/CU (v4) ================
// Proven structure (R7): 256 thr = 4 waves (2M x 2N), BK=64, 64 KiB dbuf LDS
// -> 2 blocks/CU; 4 phases / 2 K-tiles, counted vmcnt(4); chunk-XOR swizzle
// both sides; inline-asm ds_read; setprio.
// OUT: 1 = f32 out; 2 = f32 + residual; 3 = fp8 e4m3 out (value path).
template<int OUT>
__global__ __launch_bounds__(256, 2) void gemm128p(
    const u16* __restrict__ A, const u16* __restrict__ Bt,
    const float* __restrict__ bias, const float* __restrict__ res,
    void* __restrict__ Cout, int M, int N, int K, int nbx)
{
  __shared__ u16 lds[2][2][128*64];
  const int nwg = gridDim.x;                       // multiple of 8
  const int bid = blockIdx.x;
  const int swz = (bid & 7) * (nwg >> 3) + (bid >> 3);
  const int bx = swz % nbx, by = swz / nbx;
  const int m0 = by*128, n0 = bx*128;
  const int t = threadIdx.x, w = t >> 6, lane = t & 63;
  const int wr = w >> 1, wc = w & 1;
  const int NT = K >> 6;
  const int lr = lane & 15;

  const int stColU = (((t & 7) ^ ((t >> 3) & 7)) << 3);

  f32x4 acc[4][4];
  #pragma unroll
  for (int mi=0;mi<4;mi++)
    #pragma unroll
    for (int ni=0;ni<4;ni++)
      acc[mi][ni] = (f32x4){0.f,0.f,0.f,0.f};

  #define STG(op, half, kt, buf, G, gbase)                                     \
    { const u16* g_ = (G) + (size_t)((gbase) + (half)*64 + (t>>3))*K           \
                          + (kt)*64 + stColU;                                  \
      u16* l_ = &lds[buf][op][(half)*64*64 + (w<<9)];                          \
      __builtin_amdgcn_global_load_lds(GLOBAL_AS(g_), LDS_AS(l_), 16,0,0);     \
      __builtin_amdgcn_global_load_lds(GLOBAL_AS(g_ + (size_t)32*K),           \
                                       LDS_AS(l_ + 2048), 16,0,0); }

  const int slot0 = (((lane>>4)    ) ^ (lane&7)) * 8;   // kk=0
  const int slot1 = (((lane>>4) + 4) ^ (lane&7)) * 8;   // kk=1

  STG(1,0,0,0, Bt, n0); STG(1,1,0,0, Bt, n0);
  STG(0,0,0,0, A,  m0); STG(0,1,0,0, A,  m0);
  STG(1,0,1,1, Bt, n0); STG(1,1,1,1, Bt, n0);
  asm volatile("s_waitcnt vmcnt(4)" ::: "memory");
  __builtin_amdgcn_s_barrier();

  const u16* lA0 = &lds[0][0][(wr*64 + lr)*64];
  const u16* lB0 = &lds[0][1][(wc*64 + lr)*64];
  const u16* lA1 = &lds[1][0][(wr*64 + lr)*64];
  const u16* lB1 = &lds[1][1][(wc*64 + lr)*64];

  short8 bf_[4][2], aR[4];

  #define DSR(dst_, p_)                                                        \
    asm volatile("ds_read_b128 %0, %1" : "=v"(dst_) : "v"((lds_cp)(p_)))

  #define READ_A4(lA_, jp_)                                                    \
    DSR(aR[0], (lA_) + ((jp_)*32     )*64 + slot0);                            \
    DSR(aR[1], (lA_) + ((jp_)*32     )*64 + slot1);                            \
    DSR(aR[2], (lA_) + ((jp_)*32 + 16)*64 + slot0);                            \
    DSR(aR[3], (lA_) + ((jp_)*32 + 16)*64 + slot1);

  #define READ_B8(lB_)                                                         \
    DSR(bf_[0][0], (lB_) +  0*64 + slot0);  DSR(bf_[0][1], (lB_) +  0*64 + slot1); \
    DSR(bf_[1][0], (lB_) + 16*64 + slot0);  DSR(bf_[1][1], (lB_) + 16*64 + slot1); \
    DSR(bf_[2][0], (lB_) + 32*64 + slot0);  DSR(bf_[2][1], (lB_) + 32*64 + slot1); \
    DSR(bf_[3][0], (lB_) + 48*64 + slot0);  DSR(bf_[3][1], (lB_) + 48*64 + slot1);

  #define MFMA16(jp_)                                                          \
    _Pragma("unroll")                                                          \
    for (int ni=0; ni<4; ++ni) {                                               \
      acc[2*(jp_)  ][ni] = __builtin_amdgcn_mfma_f32_16x16x32_bf16(aR[0], bf_[ni][0], acc[2*(jp_)  ][ni], 0,0,0); \
      acc[2*(jp_)  ][ni] = __builtin_amdgcn_mfma_f32_16x16x32_bf16(aR[1], bf_[ni][1], acc[2*(jp_)  ][ni], 0,0,0); \
      acc[2*(jp_)+1][ni] = __builtin_amdgcn_mfma_f32_16x16x32_bf16(aR[2], bf_[ni][0], acc[2*(jp_)+1][ni], 0,0,0); \
      acc[2*(jp_)+1][ni] = __builtin_amdgcn_mfma_f32_16x16x32_bf16(aR[3], bf_[ni][1], acc[2*(jp_)+1][ni], 0,0,0); \
    }

  #define LGKM0 do { asm volatile("s_waitcnt lgkmcnt(0)" ::: "memory");        \
                     __builtin_amdgcn_sched_barrier(0); } while(0)
  #define BAR   __builtin_amdgcn_s_barrier()
  #define VM4   asm volatile("s_waitcnt vmcnt(4)" ::: "memory")
  #define SETP1 __builtin_amdgcn_s_setprio(1)
  #define SETP0 __builtin_amdgcn_s_setprio(0)

  const int NITER = NT >> 1;
  for (int i = 0; i < NITER; ++i) {
    const int bt = 2*i + 1;
    const int a2 = (2*i+2 < NT) ? 2*i+2 : NT-1;
    const int b2 = (2*i+3 < NT) ? 2*i+3 : NT-1;

    READ_B8(lB0); READ_A4(lA0, 0);
    STG(0,0,bt,1, A, m0); STG(0,1,bt,1, A, m0);
    BAR; LGKM0;
    SETP1; MFMA16(0); SETP0;
    BAR;

    READ_A4(lA0, 1);
    STG(1,0,a2,0, Bt, n0); STG(1,1,a2,0, Bt, n0);
    BAR; LGKM0;
    SETP1; MFMA16(1); SETP0;
    VM4; BAR;

    READ_B8(lB1); READ_A4(lA1, 0);
    STG(0,0,a2,0, A, m0); STG(0,1,a2,0, A, m0);
    BAR; LGKM0;
    SETP1; MFMA16(0); SETP0;
    BAR;

    READ_A4(lA1, 1);
    STG(1,0,b2,1, Bt, n0); STG(1,1,b2,1, Bt, n0);
    BAR; LGKM0;
    SETP1; MFMA16(1); SETP0;
    VM4; BAR;
  }
  #undef STG
  #undef READ_A4
  #undef READ_B8
  #undef MFMA16
  #undef DSR
  #undef VM4

  // ---- epilogue: restage C (f32, bias added) through LDS ----
  asm volatile("s_waitcnt vmcnt(0)" ::: "memory");
  BAR;
  float* lsf = (float*)lds;                        // 128x128 f32 = 64 KiB
  #pragma unroll
  for (int ni=0;ni<4;ni++){
    const int col = wc*64 + ni*16 + lr;
    const float bc = bias[n0 + col];
    #pragma unroll
    for (int mi=0;mi<4;mi++){
      const int row0 = wr*64 + mi*16 + (lane>>4)*4;
      #pragma unroll
      for (int r=0;r<4;r++)
        lsf[(row0+r)*128 + col] = acc[mi][ni][r] + bc;
    }
  }
  asm volatile("s_waitcnt lgkmcnt(0)" ::: "memory");
  BAR;
  if constexpr (OUT == 3) {
    u8* C = (u8*)Cout;
    #pragma unroll
    for (int it=0; it<16; ++it){
      const int c = t + 256*it;                    // 4-col f32 chunk id
      const int row = c >> 5, col4 = (c & 31) << 2;
      f32x4 v = *(const f32x4*)(lsf + ((size_t)c << 2));
      *(uint32_t*)(&C[(size_t)(m0 + row)*N + n0 + col4]) = enc4(v);
    }
  } else {
    float* C = (float*)Cout;
    #pragma unroll
    for (int it=0; it<16; ++it){
      const int c = t + 256*it;                    // 16B chunk id (4 f32)
      const int row = c >> 5, col4 = (c & 31) << 2;
      f32x4 v = *(const f32x4*)(lsf + ((size_t)c << 2));
      if constexpr (OUT == 2) {
        const f32x4 rv = *(const f32x4*)(&res[(size_t)(m0 + row)*N + n0 + col4]);
        v = v + rv;
      }
      *(f32x4*)(&C[(size_t)(m0 + row)*N + n0 + col4]) = v;
    }
  }
  #undef BAR
  #undef LGKM0
  #undef SETP1
  #undef SETP0
}

// ---------------- deformable sampling + attention-weighted accumulate ------
// R9 shape (proven best): 192 thr = 2 queries x 96 threads, 8 B gathers,
// grouped-4 gather batching (R11, neutral but kept).
#define NQ_ 4096
#define LV_ 21504

__global__ __launch_bounds__(192) void sample_kernel(
    const float* __restrict__ offattn, const float* __restrict__ refp,
    const u8* __restrict__ value, u16* __restrict__ accb)
{
  __shared__ float s_w[2][4][72];
  __shared__ int   s_idx[2][4][72];
  __shared__ float s_at[2][72];
  const int t = threadIdx.x;

  if (t < 144) {
    const int qi = t / 72, s = t % 72;
    const int bq = blockIdx.x*2 + qi;
    const float* row = offattn + (size_t)bq * 256;
    const int j = s % 12, l = j >> 2;
    const float Wf = (l==0) ? 128.f : ((l==1) ? 64.f : 32.f);
    const int   Wi = (l==0) ? 128   : ((l==1) ? 64   : 32);
    const int   st = (l==0) ? 0     : ((l==1) ? 16384 : 20480);
    const float rx = refp[((size_t)bq*3 + l)*2 + 0];
    const float ry = refp[((size_t)bq*3 + l)*2 + 1];
    const float px = rx*Wf + row[2*s]   - 0.5f;
    const float py = ry*Wf + row[2*s+1] - 0.5f;
    const float x0f = floorf(px), y0f = floorf(py);
    const int x0 = (int)x0f, y0 = (int)y0f;
    const float fx = px - x0f, fy = py - y0f;
    #pragma unroll
    for (int c=0;c<4;c++){
      const int dx = c & 1, dy = c >> 1;
      const int ix = x0 + dx, iy = y0 + dy;
      const float wgt = (dx ? fx : 1.f-fx) * (dy ? fy : 1.f-fy);
      const bool ok = (ix >= 0) && (ix < Wi) && (iy >= 0) && (iy < Wi);
      const int cx = min(max(ix,0),Wi-1), cy = min(max(iy,0),Wi-1);
      s_w[qi][c][s]   = ok ? wgt : 0.f;
      s_idx[qi][c][s] = st + cy*Wi + cx;
    }
  } else if (t < 156) {
    const int u = t - 144, qi = u / 6, h = u % 6;
    const int bq = blockIdx.x*2 + qi;
    const float* lg = offattn + (size_t)bq * 256 + 144 + h*12;
    float m = lg[0];
    #pragma unroll
    for (int j2=1;j2<12;j2++) m = fmaxf(m, lg[j2]);
    float e[12]; float sum = 0.f;
    #pragma unroll
    for (int j2=0;j2<12;j2++){ e[j2] = __expf(lg[j2]-m); sum += e[j2]; }
    const float inv = 1.f/sum;
    #pragma unroll
    for (int j2=0;j2<12;j2++) s_at[qi][h*12+j2] = e[j2]*inv;
  }
  __syncthreads();

  const int qi = t / 96, tt = t % 96;
  const int bq = blockIdx.x*2 + qi;
  const int b = bq >> 12;
  const int cb = tt * 8;          // fp8 column base (byte index)
  const int h = cb >> 7;          // head (128 cols/head)
  const u8* vb = value + (size_t)b * LV_ * 768;

  float ax[8];
  #pragma unroll
  for (int k=0;k<8;k++) ax[k] = 0.f;

  #pragma unroll
  for (int g=0; g<3; ++g){
    u32x2 uu[4][4];
    #pragma unroll
    for (int jj=0;jj<4;jj++){
      const int s = h*12 + g*4 + jj;
      #pragma unroll
      for (int c=0;c<4;c++)
        uu[jj][c] = *(const u32x2*)(vb + (size_t)s_idx[qi][c][s]*768 + cb);
    }
    #pragma unroll
    for (int jj=0;jj<4;jj++){
      const int s = h*12 + g*4 + jj;
      const float at = s_at[qi][s];
      float sx[8];
      #pragma unroll
      for (int k=0;k<8;k++) sx[k] = 0.f;
      #pragma unroll
      for (int c=0;c<4;c++){
        const float wgt = s_w[qi][c][s];
        float v[8];
        dec8(uu[jj][c], v);
        #pragma unroll
        for (int k=0;k<8;k++) sx[k] += wgt * v[k];
      }
      #pragma unroll
      for (int k=0;k<8;k++) ax[k] += at * sx[k];
    }
  }

  u16* ob = accb + (size_t)bq * 768 + cb;
  u32x4 o;
  #pragma unroll
  for (int k=0;k<4;k++)
    o[k] = ((uint32_t)f2bf(ax[2*k+1]) << 16) | (uint32_t)f2bf(ax[2*k]);
  *(u32x4*)ob = o;
}

// ---------------------------------------------------------------------------
extern "C" void kernel_launch(void* const* d_in, const int* in_sizes, int n_in,
                              void* d_out, int out_size, void* d_ws, size_t ws_size,
                              hipStream_t stream) {
  (void)in_sizes; (void)n_in; (void)out_size; (void)ws_size;
  const float* query = (const float*)d_in[0];
  const float* refp  = (const float*)d_in[1];
  const float* feat  = (const float*)d_in[2];
  const float* qn_g  = (const float*)d_in[3];
  const float* qn_b  = (const float*)d_in[4];
  const float* fn_g  = (const float*)d_in[5];
  const float* fn_b  = (const float*)d_in[6];
  const float* Wv    = (const float*)d_in[7];
  const float* bv    = (const float*)d_in[8];
  const float* Ws    = (const float*)d_in[9];
  const float* bs    = (const float*)d_in[10];
  const float* Wa    = (const float*)d_in[11];
  const float* ba    = (const float*)d_in[12];
  const float* Wo    = (const float*)d_in[13];
  const float* bo    = (const float*)d_in[14];
  float* out = (float*)d_out;

  constexpr size_t SZ_FLN  = (size_t)43008*768*2;
  constexpr size_t SZ_QLN  = (size_t)8192*768*2;
  constexpr size_t SZ_W    = (size_t)768*768*2;
  constexpr size_t SZ_WSAT = (size_t)256*768*2;
  char* ws = (char*)d_ws;
  u16*  fln   = (u16*)(ws);
  u8*   value = (u8*)(ws + SZ_FLN);               // fp8 (33 MB in 66 MB slot)
  u16*  qln   = (u16*)(ws + 2*SZ_FLN);
  u16*  Wvt   = (u16*)(ws + 2*SZ_FLN + SZ_QLN);
  u16*  Wot   = (u16*)(ws + 2*SZ_FLN + SZ_QLN + SZ_W);
  u16*  Wsat  = (u16*)(ws + 2*SZ_FLN + SZ_QLN + 2*SZ_W);
  float* bsa  = (float*)(ws + 2*SZ_FLN + SZ_QLN + 2*SZ_W + SZ_WSAT);
  float* offattn = (float*)fln;
  u16*   accb    = qln;

  // 1) weight prep (all transposes + Wsat tail zero + bsa) -- one dispatch
  prep_weights<<<1465, 256, 0, stream>>>(Wv, Wo, Ws, Wa, bs, ba,
                                         Wvt, Wot, Wsat, bsa);

  // 2) both LayerNorms -> bf16 -- one dispatch, wave-per-row, 2-row ILP
  ln_all<<<2048, 256, 0, stream>>>(query, feat, qn_g, qn_b, fn_g, fn_b,
                                   qln, fln);

  // 3) value = LN(feat) @ Wv + bv -> fp8 [43008, 768]  (336x6 = 2016 blocks)
  gemm128p<3><<<2016, 256, 0, stream>>>(fln, Wvt, bv, nullptr, value, 43008, 768, 768, 6);

  // 4) off/attn logits = LN(query) @ [Ws|Wa] -> f32 [8192, 256]  (64x2)
  gemm128p<1><<<128, 256, 0, stream>>>(qln, Wsat, bsa, nullptr, offattn, 8192, 256, 768, 2);

  // 5) deformable sampling (fp8 value) -> bf16 [8192, 768]
  sample_kernel<<<4096, 192, 0, stream>>>(offattn, refp, value, accb);

  // 6) out = acc @ Wo + bo + query -> f32  (64x6 = 384 blocks)
  gemm128p<2><<<384, 256, 0, stream>>>(accb, Wot, bo, query, out, 8192, 768, 768, 6);
}

// Round 16
// 154.035 us; speedup vs baseline: 1.0574x; 1.0574x over previous
//
#include <hip/hip_runtime.h>
#include <cstdint>
#include <cstddef>

typedef unsigned short u16;
typedef unsigned char  u8;
typedef __attribute__((ext_vector_type(8))) short short8;
typedef __attribute__((ext_vector_type(4))) float f32x4;
typedef __attribute__((ext_vector_type(2))) float f32x2;
typedef __attribute__((ext_vector_type(4))) unsigned int u32x4;
typedef __attribute__((ext_vector_type(2))) unsigned int u32x2;

#define GLOBAL_AS(p) ((const __attribute__((address_space(1))) void*)(p))
#define LDS_AS(p)    ((__attribute__((address_space(3))) void*)(p))
typedef __attribute__((address_space(3))) const void* lds_cp;

// HW fp8 converters (OCP e4m3 on gfx950), software fallback kept consistent.
#if defined(__has_builtin)
# if __has_builtin(__builtin_amdgcn_cvt_pk_f32_fp8) && __has_builtin(__builtin_amdgcn_cvt_pk_fp8_f32)
#  define HW_FP8 1
# endif
#endif

__device__ __forceinline__ float bf2f(u16 u){
  union { uint32_t u; float f; } c; c.u = ((uint32_t)u) << 16; return c.f;
}
__device__ __forceinline__ u16 f2bf(float f){
  union { float f; uint32_t u; } c; c.f = f;
  uint32_t r = c.u + 0x7fffu + ((c.u >> 16) & 1u);
  return (u16)(r >> 16);
}

__device__ __forceinline__ u8 f2fp8_sw(float x){
  float cx = fminf(fmaxf(x, -448.f), 448.f);
  union { _Float16 h; unsigned short u; } c;
  c.h = (_Float16)(cx * 0.00390625f);     // 2^-8, RNE
  unsigned short mag = c.u & 0x7fff;
  unsigned r = ((unsigned)mag + 0x3Fu + ((mag >> 7) & 1u)) >> 7;
  if (r > 0x7Eu) r = 0x7Eu;
  return (u8)(r | ((c.u >> 8) & 0x80u));
}
__device__ __forceinline__ float fp8d_sw(uint32_t b){
  union { unsigned short u; _Float16 h; } c;
  c.u = (unsigned short)(((b & 0x7fu) << 7) | ((b & 0x80u) << 8));
  return (float)c.h * 256.f;              // true value
}
__device__ __forceinline__ uint32_t enc4(f32x4 v){
#ifdef HW_FP8
  int p = __builtin_amdgcn_cvt_pk_fp8_f32(v[0], v[1], 0, false);
  p     = __builtin_amdgcn_cvt_pk_fp8_f32(v[2], v[3], p, true);
  return (uint32_t)p;
#else
  return (uint32_t)f2fp8_sw(v[0]) | ((uint32_t)f2fp8_sw(v[1]) << 8)
       | ((uint32_t)f2fp8_sw(v[2]) << 16) | ((uint32_t)f2fp8_sw(v[3]) << 24);
#endif
}
__device__ __forceinline__ void dec8(u32x2 u, float* v){
#ifdef HW_FP8
  f32x2 a = __builtin_amdgcn_cvt_pk_f32_fp8((int)u[0], false);
  f32x2 b = __builtin_amdgcn_cvt_pk_f32_fp8((int)u[0], true);
  f32x2 c = __builtin_amdgcn_cvt_pk_f32_fp8((int)u[1], false);
  f32x2 d = __builtin_amdgcn_cvt_pk_f32_fp8((int)u[1], true);
  v[0]=a[0]; v[1]=a[1]; v[2]=b[0]; v[3]=b[1];
  v[4]=c[0]; v[5]=c[1]; v[6]=d[0]; v[7]=d[1];
#else
  v[0]=fp8d_sw(u[0]      ); v[1]=fp8d_sw(u[0] >>  8);
  v[2]=fp8d_sw(u[0] >> 16); v[3]=fp8d_sw(u[0] >> 24);
  v[4]=fp8d_sw(u[1]      ); v[5]=fp8d_sw(u[1] >>  8);
  v[6]=fp8d_sw(u[1] >> 16); v[7]=fp8d_sw(u[1] >> 24);
#endif
}

// -------- fused LN + weight prep (one dispatch) ----------------------------
// Blocks 0..NLN-1: wave-per-row LayerNorm (R13's proven form, grid-stride).
// Blocks NLN..NLN+1464: weight transposes + Wsat tail zero + bsa pack.
#define NLN 4096

__device__ __forceinline__ void tcast_body(const float* __restrict__ in,
    int ld, int ncnt, u16* __restrict__ out, int bx, int by,
    float (*tile)[33])
{
  const int tx = threadIdx.x & 31, ty = threadIdx.x >> 5;
  const int n0 = bx * 32, k0 = by * 32;
  #pragma unroll
  for (int i=0;i<4;i++){
    int k = k0 + ty + 8*i, n = n0 + tx;
    tile[ty+8*i][tx] = (n < ncnt) ? in[(size_t)k*ld + n] : 0.f;
  }
  __syncthreads();
  #pragma unroll
  for (int i=0;i<4;i++){
    int n = n0 + ty + 8*i, k = k0 + tx;
    if (n < ncnt) out[(size_t)n*768 + k] = f2bf(tile[tx][ty+8*i]);
  }
}

__global__ __launch_bounds__(256) void ln_prep(
    const float* __restrict__ q, const float* __restrict__ f,
    const float* __restrict__ qg, const float* __restrict__ qb,
    const float* __restrict__ fg, const float* __restrict__ fb,
    u16* __restrict__ qout, u16* __restrict__ fout,
    const float* __restrict__ Wv, const float* __restrict__ Wo,
    const float* __restrict__ Ws, const float* __restrict__ Wa,
    const float* __restrict__ bs, const float* __restrict__ ba,
    u16* __restrict__ Wvt, u16* __restrict__ Wot,
    u16* __restrict__ Wsat, float* __restrict__ bsa)
{
  __shared__ float tile[32][33];
  const int blkid = blockIdx.x;
  if (blkid < NLN) {
    // ---- LayerNorm path (R13 proven) ----
    const int lane = threadIdx.x & 63;
    const int gw = blkid * 4 + (threadIdx.x >> 6);
    const int nw = NLN * 4;
    const int c4 = lane * 4;
    for (int ri = gw; ri < 51200; ri += nw) {
      const bool isq = ri < 8192;
      const size_t row = isq ? (size_t)ri : (size_t)(ri - 8192);
      const float* xr = (isq ? q : f) + row * 768;
      const float* g   = isq ? qg : fg;
      const float* bta = isq ? qb : fb;
      u16* yr = (isq ? qout : fout) + row * 768;

      const f32x4 v0 = *(const f32x4*)(xr + c4);
      const f32x4 v1 = *(const f32x4*)(xr + 256 + c4);
      const f32x4 v2 = *(const f32x4*)(xr + 512 + c4);

      float s  = v0[0]+v0[1]+v0[2]+v0[3] + v1[0]+v1[1]+v1[2]+v1[3]
               + v2[0]+v2[1]+v2[2]+v2[3];
      float qq = v0[0]*v0[0]+v0[1]*v0[1]+v0[2]*v0[2]+v0[3]*v0[3]
               + v1[0]*v1[0]+v1[1]*v1[1]+v1[2]*v1[2]+v1[3]*v1[3]
               + v2[0]*v2[0]+v2[1]*v2[1]+v2[2]*v2[2]+v2[3]*v2[3];
      #pragma unroll
      for (int o=1;o<64;o<<=1){ s += __shfl_xor(s,o); qq += __shfl_xor(qq,o); }
      const float m = s * (1.f/768.f);
      const float var = qq * (1.f/768.f) - m*m;
      const float rstd = rsqrtf(var + 1e-6f);

      #pragma unroll
      for (int r=0;r<3;r++){
        const f32x4 v = (r==0) ? v0 : ((r==1) ? v1 : v2);
        const f32x4 gg = *(const f32x4*)(g   + r*256 + c4);
        const f32x4 bb = *(const f32x4*)(bta + r*256 + c4);
        u32x2 p;
        p[0] = (uint32_t)f2bf((v[0]-m)*rstd*gg[0] + bb[0])
             | ((uint32_t)f2bf((v[1]-m)*rstd*gg[1] + bb[1]) << 16);
        p[1] = (uint32_t)f2bf((v[2]-m)*rstd*gg[2] + bb[2])
             | ((uint32_t)f2bf((v[3]-m)*rstd*gg[3] + bb[3]) << 16);
        *(u32x2*)(yr + r*256 + c4) = p;
      }
    }
    return;
  }
  // ---- weight prep path ----
  const int blk = blkid - NLN;
  if (blk < 576) {
    tcast_body(Wv, 768, 768, Wvt, blk % 24, blk / 24, tile);
  } else if (blk < 1152) {
    const int sub = blk - 576;
    tcast_body(Wo, 768, 768, Wot, sub % 24, sub / 24, tile);
  } else if (blk < 1272) {
    const int sub = blk - 1152;
    tcast_body(Ws, 144, 144, Wsat, sub % 5, sub / 5, tile);
  } else if (blk < 1344) {
    const int sub = blk - 1272;
    tcast_body(Wa, 72, 72, Wsat + (size_t)144*768, sub % 3, sub / 3, tile);
  } else if (blk < 1464) {
    const int sub = blk - 1344;          // zero rows 216..255 of Wsat
    Wsat[(size_t)216*768 + sub*256 + threadIdx.x] = 0;
  } else {
    const int t = threadIdx.x;
    bsa[t] = (t < 144) ? bs[t] : ((t < 216) ? ba[t-144] : 0.f);
  }
}

// ============ 128x128 pipelined MFMA GEMM, 2 blocks/CU (v4) ================
// Proven structure (R7): 256 thr = 4 waves (2M x 2N), BK=64, 64 KiB dbuf LDS
// -> 2 blocks/CU; 4 phases / 2 K-tiles, counted vmcnt(4); chunk-XOR swizzle
// both sides; inline-asm ds_read; setprio.
// OUT: 1 = f32 out; 2 = f32 + residual; 3 = fp8 e4m3 out (value path).
template<int OUT>
__global__ __launch_bounds__(256, 2) void gemm128p(
    const u16* __restrict__ A, const u16* __restrict__ Bt,
    const float* __restrict__ bias, const float* __restrict__ res,
    void* __restrict__ Cout, int M, int N, int K, int nbx)
{
  __shared__ u16 lds[2][2][128*64];
  const int nwg = gridDim.x;                       // multiple of 8
  const int bid = blockIdx.x;
  const int swz = (bid & 7) * (nwg >> 3) + (bid >> 3);
  const int bx = swz % nbx, by = swz / nbx;
  const int m0 = by*128, n0 = bx*128;
  const int t = threadIdx.x, w = t >> 6, lane = t & 63;
  const int wr = w >> 1, wc = w & 1;
  const int NT = K >> 6;
  const int lr = lane & 15;

  const int stColU = (((t & 7) ^ ((t >> 3) & 7)) << 3);

  f32x4 acc[4][4];
  #pragma unroll
  for (int mi=0;mi<4;mi++)
    #pragma unroll
    for (int ni=0;ni<4;ni++)
      acc[mi][ni] = (f32x4){0.f,0.f,0.f,0.f};

  #define STG(op, half, kt, buf, G, gbase)                                     \
    { const u16* g_ = (G) + (size_t)((gbase) + (half)*64 + (t>>3))*K           \
                          + (kt)*64 + stColU;                                  \
      u16* l_ = &lds[buf][op][(half)*64*64 + (w<<9)];                          \
      __builtin_amdgcn_global_load_lds(GLOBAL_AS(g_), LDS_AS(l_), 16,0,0);     \
      __builtin_amdgcn_global_load_lds(GLOBAL_AS(g_ + (size_t)32*K),           \
                                       LDS_AS(l_ + 2048), 16,0,0); }

  const int slot0 = (((lane>>4)    ) ^ (lane&7)) * 8;   // kk=0
  const int slot1 = (((lane>>4) + 4) ^ (lane&7)) * 8;   // kk=1

  STG(1,0,0,0, Bt, n0); STG(1,1,0,0, Bt, n0);
  STG(0,0,0,0, A,  m0); STG(0,1,0,0, A,  m0);
  STG(1,0,1,1, Bt, n0); STG(1,1,1,1, Bt, n0);
  asm volatile("s_waitcnt vmcnt(4)" ::: "memory");
  __builtin_amdgcn_s_barrier();

  const u16* lA0 = &lds[0][0][(wr*64 + lr)*64];
  const u16* lB0 = &lds[0][1][(wc*64 + lr)*64];
  const u16* lA1 = &lds[1][0][(wr*64 + lr)*64];
  const u16* lB1 = &lds[1][1][(wc*64 + lr)*64];

  short8 bf_[4][2], aR[4];

  #define DSR(dst_, p_)                                                        \
    asm volatile("ds_read_b128 %0, %1" : "=v"(dst_) : "v"((lds_cp)(p_)))

  #define READ_A4(lA_, jp_)                                                    \
    DSR(aR[0], (lA_) + ((jp_)*32     )*64 + slot0);                            \
    DSR(aR[1], (lA_) + ((jp_)*32     )*64 + slot1);                            \
    DSR(aR[2], (lA_) + ((jp_)*32 + 16)*64 + slot0);                            \
    DSR(aR[3], (lA_) + ((jp_)*32 + 16)*64 + slot1);

  #define READ_B8(lB_)                                                         \
    DSR(bf_[0][0], (lB_) +  0*64 + slot0);  DSR(bf_[0][1], (lB_) +  0*64 + slot1); \
    DSR(bf_[1][0], (lB_) + 16*64 + slot0);  DSR(bf_[1][1], (lB_) + 16*64 + slot1); \
    DSR(bf_[2][0], (lB_) + 32*64 + slot0);  DSR(bf_[2][1], (lB_) + 32*64 + slot1); \
    DSR(bf_[3][0], (lB_) + 48*64 + slot0);  DSR(bf_[3][1], (lB_) + 48*64 + slot1);

  #define MFMA16(jp_)                                                          \
    _Pragma("unroll")                                                          \
    for (int ni=0; ni<4; ++ni) {                                               \
      acc[2*(jp_)  ][ni] = __builtin_amdgcn_mfma_f32_16x16x32_bf16(aR[0], bf_[ni][0], acc[2*(jp_)  ][ni], 0,0,0); \
      acc[2*(jp_)  ][ni] = __builtin_amdgcn_mfma_f32_16x16x32_bf16(aR[1], bf_[ni][1], acc[2*(jp_)  ][ni], 0,0,0); \
      acc[2*(jp_)+1][ni] = __builtin_amdgcn_mfma_f32_16x16x32_bf16(aR[2], bf_[ni][0], acc[2*(jp_)+1][ni], 0,0,0); \
      acc[2*(jp_)+1][ni] = __builtin_amdgcn_mfma_f32_16x16x32_bf16(aR[3], bf_[ni][1], acc[2*(jp_)+1][ni], 0,0,0); \
    }

  #define LGKM0 do { asm volatile("s_waitcnt lgkmcnt(0)" ::: "memory");        \
                     __builtin_amdgcn_sched_barrier(0); } while(0)
  #define BAR   __builtin_amdgcn_s_barrier()
  #define VM4   asm volatile("s_waitcnt vmcnt(4)" ::: "memory")
  #define SETP1 __builtin_amdgcn_s_setprio(1)
  #define SETP0 __builtin_amdgcn_s_setprio(0)

  const int NITER = NT >> 1;
  for (int i = 0; i < NITER; ++i) {
    const int bt = 2*i + 1;
    const int a2 = (2*i+2 < NT) ? 2*i+2 : NT-1;
    const int b2 = (2*i+3 < NT) ? 2*i+3 : NT-1;

    READ_B8(lB0); READ_A4(lA0, 0);
    STG(0,0,bt,1, A, m0); STG(0,1,bt,1, A, m0);
    BAR; LGKM0;
    SETP1; MFMA16(0); SETP0;
    BAR;

    READ_A4(lA0, 1);
    STG(1,0,a2,0, Bt, n0); STG(1,1,a2,0, Bt, n0);
    BAR; LGKM0;
    SETP1; MFMA16(1); SETP0;
    VM4; BAR;

    READ_B8(lB1); READ_A4(lA1, 0);
    STG(0,0,a2,0, A, m0); STG(0,1,a2,0, A, m0);
    BAR; LGKM0;
    SETP1; MFMA16(0); SETP0;
    BAR;

    READ_A4(lA1, 1);
    STG(1,0,b2,1, Bt, n0); STG(1,1,b2,1, Bt, n0);
    BAR; LGKM0;
    SETP1; MFMA16(1); SETP0;
    VM4; BAR;
  }
  #undef STG
  #undef READ_A4
  #undef READ_B8
  #undef MFMA16
  #undef DSR
  #undef VM4

  // ---- epilogue: restage C (f32, bias added) through LDS ----
  asm volatile("s_waitcnt vmcnt(0)" ::: "memory");
  BAR;
  float* lsf = (float*)lds;                        // 128x128 f32 = 64 KiB
  #pragma unroll
  for (int ni=0;ni<4;ni++){
    const int col = wc*64 + ni*16 + lr;
    const float bc = bias[n0 + col];
    #pragma unroll
    for (int mi=0;mi<4;mi++){
      const int row0 = wr*64 + mi*16 + (lane>>4)*4;
      #pragma unroll
      for (int r=0;r<4;r++)
        lsf[(row0+r)*128 + col] = acc[mi][ni][r] + bc;
    }
  }
  asm volatile("s_waitcnt lgkmcnt(0)" ::: "memory");
  BAR;
  if constexpr (OUT == 3) {
    u8* C = (u8*)Cout;
    #pragma unroll
    for (int it=0; it<16; ++it){
      const int c = t + 256*it;                    // 4-col f32 chunk id
      const int row = c >> 5, col4 = (c & 31) << 2;
      f32x4 v = *(const f32x4*)(lsf + ((size_t)c << 2));
      *(uint32_t*)(&C[(size_t)(m0 + row)*N + n0 + col4]) = enc4(v);
    }
  } else {
    float* C = (float*)Cout;
    #pragma unroll
    for (int it=0; it<16; ++it){
      const int c = t + 256*it;                    // 16B chunk id (4 f32)
      const int row = c >> 5, col4 = (c & 31) << 2;
      f32x4 v = *(const f32x4*)(lsf + ((size_t)c << 2));
      if constexpr (OUT == 2) {
        const f32x4 rv = *(const f32x4*)(&res[(size_t)(m0 + row)*N + n0 + col4]);
        v = v + rv;
      }
      *(f32x4*)(&C[(size_t)(m0 + row)*N + n0 + col4]) = v;
    }
  }
  #undef BAR
  #undef LGKM0
  #undef SETP1
  #undef SETP0
}

// ---------------- deformable sampling + attention-weighted accumulate ------
// R9 shape (proven best): 192 thr = 2 queries x 96 threads, 8 B gathers,
// grouped-4 gather batching (R11, neutral but kept).
#define NQ_ 4096
#define LV_ 21504

__global__ __launch_bounds__(192) void sample_kernel(
    const float* __restrict__ offattn, const float* __restrict__ refp,
    const u8* __restrict__ value, u16* __restrict__ accb)
{
  __shared__ float s_w[2][4][72];
  __shared__ int   s_idx[2][4][72];
  __shared__ float s_at[2][72];
  const int t = threadIdx.x;

  if (t < 144) {
    const int qi = t / 72, s = t % 72;
    const int bq = blockIdx.x*2 + qi;
    const float* row = offattn + (size_t)bq * 256;
    const int j = s % 12, l = j >> 2;
    const float Wf = (l==0) ? 128.f : ((l==1) ? 64.f : 32.f);
    const int   Wi = (l==0) ? 128   : ((l==1) ? 64   : 32);
    const int   st = (l==0) ? 0     : ((l==1) ? 16384 : 20480);
    const float rx = refp[((size_t)bq*3 + l)*2 + 0];
    const float ry = refp[((size_t)bq*3 + l)*2 + 1];
    const float px = rx*Wf + row[2*s]   - 0.5f;
    const float py = ry*Wf + row[2*s+1] - 0.5f;
    const float x0f = floorf(px), y0f = floorf(py);
    const int x0 = (int)x0f, y0 = (int)y0f;
    const float fx = px - x0f, fy = py - y0f;
    #pragma unroll
    for (int c=0;c<4;c++){
      const int dx = c & 1, dy = c >> 1;
      const int ix = x0 + dx, iy = y0 + dy;
      const float wgt = (dx ? fx : 1.f-fx) * (dy ? fy : 1.f-fy);
      const bool ok = (ix >= 0) && (ix < Wi) && (iy >= 0) && (iy < Wi);
      const int cx = min(max(ix,0),Wi-1), cy = min(max(iy,0),Wi-1);
      s_w[qi][c][s]   = ok ? wgt : 0.f;
      s_idx[qi][c][s] = st + cy*Wi + cx;
    }
  } else if (t < 156) {
    const int u = t - 144, qi = u / 6, h = u % 6;
    const int bq = blockIdx.x*2 + qi;
    const float* lg = offattn + (size_t)bq * 256 + 144 + h*12;
    float m = lg[0];
    #pragma unroll
    for (int j2=1;j2<12;j2++) m = fmaxf(m, lg[j2]);
    float e[12]; float sum = 0.f;
    #pragma unroll
    for (int j2=0;j2<12;j2++){ e[j2] = __expf(lg[j2]-m); sum += e[j2]; }
    const float inv = 1.f/sum;
    #pragma unroll
    for (int j2=0;j2<12;j2++) s_at[qi][h*12+j2] = e[j2]*inv;
  }
  __syncthreads();

  const int qi = t / 96, tt = t % 96;
  const int bq = blockIdx.x*2 + qi;
  const int b = bq >> 12;
  const int cb = tt * 8;          // fp8 column base (byte index)
  const int h = cb >> 7;          // head (128 cols/head)
  const u8* vb = value + (size_t)b * LV_ * 768;

  float ax[8];
  #pragma unroll
  for (int k=0;k<8;k++) ax[k] = 0.f;

  #pragma unroll
  for (int g=0; g<3; ++g){
    u32x2 uu[4][4];
    #pragma unroll
    for (int jj=0;jj<4;jj++){
      const int s = h*12 + g*4 + jj;
      #pragma unroll
      for (int c=0;c<4;c++)
        uu[jj][c] = *(const u32x2*)(vb + (size_t)s_idx[qi][c][s]*768 + cb);
    }
    #pragma unroll
    for (int jj=0;jj<4;jj++){
      const int s = h*12 + g*4 + jj;
      const float at = s_at[qi][s];
      float sx[8];
      #pragma unroll
      for (int k=0;k<8;k++) sx[k] = 0.f;
      #pragma unroll
      for (int c=0;c<4;c++){
        const float wgt = s_w[qi][c][s];
        float v[8];
        dec8(uu[jj][c], v);
        #pragma unroll
        for (int k=0;k<8;k++) sx[k] += wgt * v[k];
      }
      #pragma unroll
      for (int k=0;k<8;k++) ax[k] += at * sx[k];
    }
  }

  u16* ob = accb + (size_t)bq * 768 + cb;
  u32x4 o;
  #pragma unroll
  for (int k=0;k<4;k++)
    o[k] = ((uint32_t)f2bf(ax[2*k+1]) << 16) | (uint32_t)f2bf(ax[2*k]);
  *(u32x4*)ob = o;
}

// ---------------------------------------------------------------------------
extern "C" void kernel_launch(void* const* d_in, const int* in_sizes, int n_in,
                              void* d_out, int out_size, void* d_ws, size_t ws_size,
                              hipStream_t stream) {
  (void)in_sizes; (void)n_in; (void)out_size; (void)ws_size;
  const float* query = (const float*)d_in[0];
  const float* refp  = (const float*)d_in[1];
  const float* feat  = (const float*)d_in[2];
  const float* qn_g  = (const float*)d_in[3];
  const float* qn_b  = (const float*)d_in[4];
  const float* fn_g  = (const float*)d_in[5];
  const float* fn_b  = (const float*)d_in[6];
  const float* Wv    = (const float*)d_in[7];
  const float* bv    = (const float*)d_in[8];
  const float* Ws    = (const float*)d_in[9];
  const float* bs    = (const float*)d_in[10];
  const float* Wa    = (const float*)d_in[11];
  const float* ba    = (const float*)d_in[12];
  const float* Wo    = (const float*)d_in[13];
  const float* bo    = (const float*)d_in[14];
  float* out = (float*)d_out;

  constexpr size_t SZ_FLN  = (size_t)43008*768*2;
  constexpr size_t SZ_QLN  = (size_t)8192*768*2;
  constexpr size_t SZ_W    = (size_t)768*768*2;
  constexpr size_t SZ_WSAT = (size_t)256*768*2;
  char* ws = (char*)d_ws;
  u16*  fln   = (u16*)(ws);
  u8*   value = (u8*)(ws + SZ_FLN);               // fp8 (33 MB in 66 MB slot)
  u16*  qln   = (u16*)(ws + 2*SZ_FLN);
  u16*  Wvt   = (u16*)(ws + 2*SZ_FLN + SZ_QLN);
  u16*  Wot   = (u16*)(ws + 2*SZ_FLN + SZ_QLN + SZ_W);
  u16*  Wsat  = (u16*)(ws + 2*SZ_FLN + SZ_QLN + 2*SZ_W);
  float* bsa  = (float*)(ws + 2*SZ_FLN + SZ_QLN + 2*SZ_W + SZ_WSAT);
  float* offattn = (float*)fln;
  u16*   accb    = qln;

  // 1) fused LN + weight prep -- one dispatch (4096 LN blocks + 1465 prep)
  ln_prep<<<NLN + 1465, 256, 0, stream>>>(query, feat, qn_g, qn_b, fn_g, fn_b,
                                          qln, fln, Wv, Wo, Ws, Wa, bs, ba,
                                          Wvt, Wot, Wsat, bsa);

  // 2) value = LN(feat) @ Wv + bv -> fp8 [43008, 768]  (336x6 = 2016 blocks)
  gemm128p<3><<<2016, 256, 0, stream>>>(fln, Wvt, bv, nullptr, value, 43008, 768, 768, 6);

  // 3) off/attn logits = LN(query) @ [Ws|Wa] -> f32 [8192, 256]  (64x2)
  gemm128p<1><<<128, 256, 0, stream>>>(qln, Wsat, bsa, nullptr, offattn, 8192, 256, 768, 2);

  // 4) deformable sampling (fp8 value) -> bf16 [8192, 768]
  sample_kernel<<<4096, 192, 0, stream>>>(offattn, refp, value, accb);

  // 5) out = acc @ Wo + bo + query -> f32  (64x6 = 384 blocks)
  gemm128p<2><<<384, 256, 0, stream>>>(accb, Wot, bo, query, out, 8192, 768, 768, 6);
}

// Round 17
// 150.206 us; speedup vs baseline: 1.0843x; 1.0255x over previous
//
#include <hip/hip_runtime.h>
#include <cstdint>
#include <cstddef>

typedef unsigned short u16;
typedef unsigned char  u8;
typedef __attribute__((ext_vector_type(8))) short short8;
typedef __attribute__((ext_vector_type(4))) float f32x4;
typedef __attribute__((ext_vector_type(2))) float f32x2;
typedef __attribute__((ext_vector_type(4))) unsigned int u32x4;
typedef __attribute__((ext_vector_type(2))) unsigned int u32x2;

#define GLOBAL_AS(p) ((const __attribute__((address_space(1))) void*)(p))
#define LDS_AS(p)    ((__attribute__((address_space(3))) void*)(p))
typedef __attribute__((address_space(3))) const void* lds_cp;

// HW fp8 converters (OCP e4m3 on gfx950), software fallback kept consistent.
#if defined(__has_builtin)
# if __has_builtin(__builtin_amdgcn_cvt_pk_f32_fp8) && __has_builtin(__builtin_amdgcn_cvt_pk_fp8_f32)
#  define HW_FP8 1
# endif
#endif

__device__ __forceinline__ float bf2f(u16 u){
  union { uint32_t u; float f; } c; c.u = ((uint32_t)u) << 16; return c.f;
}
__device__ __forceinline__ u16 f2bf(float f){
  union { float f; uint32_t u; } c; c.f = f;
  uint32_t r = c.u + 0x7fffu + ((c.u >> 16) & 1u);
  return (u16)(r >> 16);
}

__device__ __forceinline__ u8 f2fp8_sw(float x){
  float cx = fminf(fmaxf(x, -448.f), 448.f);
  union { _Float16 h; unsigned short u; } c;
  c.h = (_Float16)(cx * 0.00390625f);     // 2^-8, RNE
  unsigned short mag = c.u & 0x7fff;
  unsigned r = ((unsigned)mag + 0x3Fu + ((mag >> 7) & 1u)) >> 7;
  if (r > 0x7Eu) r = 0x7Eu;
  return (u8)(r | ((c.u >> 8) & 0x80u));
}
__device__ __forceinline__ float fp8d_sw(uint32_t b){
  union { unsigned short u; _Float16 h; } c;
  c.u = (unsigned short)(((b & 0x7fu) << 7) | ((b & 0x80u) << 8));
  return (float)c.h * 256.f;              // true value
}
__device__ __forceinline__ uint32_t enc4(f32x4 v){
#ifdef HW_FP8
  int p = __builtin_amdgcn_cvt_pk_fp8_f32(v[0], v[1], 0, false);
  p     = __builtin_amdgcn_cvt_pk_fp8_f32(v[2], v[3], p, true);
  return (uint32_t)p;
#else
  return (uint32_t)f2fp8_sw(v[0]) | ((uint32_t)f2fp8_sw(v[1]) << 8)
       | ((uint32_t)f2fp8_sw(v[2]) << 16) | ((uint32_t)f2fp8_sw(v[3]) << 24);
#endif
}
__device__ __forceinline__ void dec8(u32x2 u, float* v){
#ifdef HW_FP8
  f32x2 a = __builtin_amdgcn_cvt_pk_f32_fp8((int)u[0], false);
  f32x2 b = __builtin_amdgcn_cvt_pk_f32_fp8((int)u[0], true);
  f32x2 c = __builtin_amdgcn_cvt_pk_f32_fp8((int)u[1], false);
  f32x2 d = __builtin_amdgcn_cvt_pk_f32_fp8((int)u[1], true);
  v[0]=a[0]; v[1]=a[1]; v[2]=b[0]; v[3]=b[1];
  v[4]=c[0]; v[5]=c[1]; v[6]=d[0]; v[7]=d[1];
#else
  v[0]=fp8d_sw(u[0]      ); v[1]=fp8d_sw(u[0] >>  8);
  v[2]=fp8d_sw(u[0] >> 16); v[3]=fp8d_sw(u[0] >> 24);
  v[4]=fp8d_sw(u[1]      ); v[5]=fp8d_sw(u[1] >>  8);
  v[6]=fp8d_sw(u[1] >> 16); v[7]=fp8d_sw(u[1] >> 24);
#endif
}

// -------- fused LN + weight prep (one dispatch) ----------------------------
#define NLN 4096

__device__ __forceinline__ void tcast_body(const float* __restrict__ in,
    int ld, int ncnt, u16* __restrict__ out, int bx, int by,
    float (*tile)[33])
{
  const int tx = threadIdx.x & 31, ty = threadIdx.x >> 5;
  const int n0 = bx * 32, k0 = by * 32;
  #pragma unroll
  for (int i=0;i<4;i++){
    int k = k0 + ty + 8*i, n = n0 + tx;
    tile[ty+8*i][tx] = (n < ncnt) ? in[(size_t)k*ld + n] : 0.f;
  }
  __syncthreads();
  #pragma unroll
  for (int i=0;i<4;i++){
    int n = n0 + ty + 8*i, k = k0 + tx;
    if (n < ncnt) out[(size_t)n*768 + k] = f2bf(tile[tx][ty+8*i]);
  }
}

__global__ __launch_bounds__(256) void ln_prep(
    const float* __restrict__ q, const float* __restrict__ f,
    const float* __restrict__ qg, const float* __restrict__ qb,
    const float* __restrict__ fg, const float* __restrict__ fb,
    u16* __restrict__ qout, u16* __restrict__ fout,
    const float* __restrict__ Wv, const float* __restrict__ Wo,
    const float* __restrict__ Ws, const float* __restrict__ Wa,
    const float* __restrict__ bs, const float* __restrict__ ba,
    u16* __restrict__ Wvt, u16* __restrict__ Wot,
    u16* __restrict__ Wsat, float* __restrict__ bsa)
{
  __shared__ float tile[32][33];
  const int blkid = blockIdx.x;
  if (blkid < NLN) {
    const int lane = threadIdx.x & 63;
    const int gw = blkid * 4 + (threadIdx.x >> 6);
    const int nw = NLN * 4;
    const int c4 = lane * 4;
    for (int ri = gw; ri < 51200; ri += nw) {
      const bool isq = ri < 8192;
      const size_t row = isq ? (size_t)ri : (size_t)(ri - 8192);
      const float* xr = (isq ? q : f) + row * 768;
      const float* g   = isq ? qg : fg;
      const float* bta = isq ? qb : fb;
      u16* yr = (isq ? qout : fout) + row * 768;

      const f32x4 v0 = *(const f32x4*)(xr + c4);
      const f32x4 v1 = *(const f32x4*)(xr + 256 + c4);
      const f32x4 v2 = *(const f32x4*)(xr + 512 + c4);

      float s  = v0[0]+v0[1]+v0[2]+v0[3] + v1[0]+v1[1]+v1[2]+v1[3]
               + v2[0]+v2[1]+v2[2]+v2[3];
      float qq = v0[0]*v0[0]+v0[1]*v0[1]+v0[2]*v0[2]+v0[3]*v0[3]
               + v1[0]*v1[0]+v1[1]*v1[1]+v1[2]*v1[2]+v1[3]*v1[3]
               + v2[0]*v2[0]+v2[1]*v2[1]+v2[2]*v2[2]+v2[3]*v2[3];
      #pragma unroll
      for (int o=1;o<64;o<<=1){ s += __shfl_xor(s,o); qq += __shfl_xor(qq,o); }
      const float m = s * (1.f/768.f);
      const float var = qq * (1.f/768.f) - m*m;
      const float rstd = rsqrtf(var + 1e-6f);

      #pragma unroll
      for (int r=0;r<3;r++){
        const f32x4 v = (r==0) ? v0 : ((r==1) ? v1 : v2);
        const f32x4 gg = *(const f32x4*)(g   + r*256 + c4);
        const f32x4 bb = *(const f32x4*)(bta + r*256 + c4);
        u32x2 p;
        p[0] = (uint32_t)f2bf((v[0]-m)*rstd*gg[0] + bb[0])
             | ((uint32_t)f2bf((v[1]-m)*rstd*gg[1] + bb[1]) << 16);
        p[1] = (uint32_t)f2bf((v[2]-m)*rstd*gg[2] + bb[2])
             | ((uint32_t)f2bf((v[3]-m)*rstd*gg[3] + bb[3]) << 16);
        *(u32x2*)(yr + r*256 + c4) = p;
      }
    }
    return;
  }
  const int blk = blkid - NLN;
  if (blk < 576) {
    tcast_body(Wv, 768, 768, Wvt, blk % 24, blk / 24, tile);
  } else if (blk < 1152) {
    const int sub = blk - 576;
    tcast_body(Wo, 768, 768, Wot, sub % 24, sub / 24, tile);
  } else if (blk < 1272) {
    const int sub = blk - 1152;
    tcast_body(Ws, 144, 144, Wsat, sub % 5, sub / 5, tile);
  } else if (blk < 1344) {
    const int sub = blk - 1272;
    tcast_body(Wa, 72, 72, Wsat + (size_t)144*768, sub % 3, sub / 3, tile);
  } else if (blk < 1464) {
    const int sub = blk - 1344;
    Wsat[(size_t)216*768 + sub*256 + threadIdx.x] = 0;
  } else {
    const int t = threadIdx.x;
    bsa[t] = (t < 144) ? bs[t] : ((t < 216) ? ba[t-144] : 0.f);
  }
}

// ============ 128x128 pipelined MFMA GEMM body (device fn) =================
// Proven structure (R7): 4 waves (2M x 2N), BK=64, 64 KiB dbuf LDS ->
// 2 blocks/CU; 4 phases / 2 K-tiles, counted vmcnt(4); chunk-XOR swizzle
// both sides; inline-asm ds_read; setprio.
// OUTK: 1 = f32 out; 2 = f32 + residual; 3 = fp8 e4m3 out.
template<int OUTK>
__device__ __forceinline__ void gemm_body(
    const u16* __restrict__ A, const u16* __restrict__ Bt,
    const float* __restrict__ bias, const float* __restrict__ res,
    void* __restrict__ Cout, int N, int K, int nbx, int bid, int nwg,
    u16 (*lds)[2][128*64])
{
  const int swz = (bid & 7) * (nwg >> 3) + (bid >> 3);
  const int bx = swz % nbx, by = swz / nbx;
  const int m0 = by*128, n0 = bx*128;
  const int t = threadIdx.x, w = t >> 6, lane = t & 63;
  const int wr = w >> 1, wc = w & 1;
  const int NT = K >> 6;
  const int lr = lane & 15;

  const int stColU = (((t & 7) ^ ((t >> 3) & 7)) << 3);

  f32x4 acc[4][4];
  #pragma unroll
  for (int mi=0;mi<4;mi++)
    #pragma unroll
    for (int ni=0;ni<4;ni++)
      acc[mi][ni] = (f32x4){0.f,0.f,0.f,0.f};

  #define STG(op, half, kt, buf, G, gbase)                                     \
    { const u16* g_ = (G) + (size_t)((gbase) + (half)*64 + (t>>3))*K           \
                          + (kt)*64 + stColU;                                  \
      u16* l_ = &lds[buf][op][(half)*64*64 + (w<<9)];                          \
      __builtin_amdgcn_global_load_lds(GLOBAL_AS(g_), LDS_AS(l_), 16,0,0);     \
      __builtin_amdgcn_global_load_lds(GLOBAL_AS(g_ + (size_t)32*K),           \
                                       LDS_AS(l_ + 2048), 16,0,0); }

  const int slot0 = (((lane>>4)    ) ^ (lane&7)) * 8;   // kk=0
  const int slot1 = (((lane>>4) + 4) ^ (lane&7)) * 8;   // kk=1

  STG(1,0,0,0, Bt, n0); STG(1,1,0,0, Bt, n0);
  STG(0,0,0,0, A,  m0); STG(0,1,0,0, A,  m0);
  STG(1,0,1,1, Bt, n0); STG(1,1,1,1, Bt, n0);
  asm volatile("s_waitcnt vmcnt(4)" ::: "memory");
  __builtin_amdgcn_s_barrier();

  const u16* lA0 = &lds[0][0][(wr*64 + lr)*64];
  const u16* lB0 = &lds[0][1][(wc*64 + lr)*64];
  const u16* lA1 = &lds[1][0][(wr*64 + lr)*64];
  const u16* lB1 = &lds[1][1][(wc*64 + lr)*64];

  short8 bf_[4][2], aR[4];

  #define DSR(dst_, p_)                                                        \
    asm volatile("ds_read_b128 %0, %1" : "=v"(dst_) : "v"((lds_cp)(p_)))

  #define READ_A4(lA_, jp_)                                                    \
    DSR(aR[0], (lA_) + ((jp_)*32     )*64 + slot0);                            \
    DSR(aR[1], (lA_) + ((jp_)*32     )*64 + slot1);                            \
    DSR(aR[2], (lA_) + ((jp_)*32 + 16)*64 + slot0);                            \
    DSR(aR[3], (lA_) + ((jp_)*32 + 16)*64 + slot1);

  #define READ_B8(lB_)                                                         \
    DSR(bf_[0][0], (lB_) +  0*64 + slot0);  DSR(bf_[0][1], (lB_) +  0*64 + slot1); \
    DSR(bf_[1][0], (lB_) + 16*64 + slot0);  DSR(bf_[1][1], (lB_) + 16*64 + slot1); \
    DSR(bf_[2][0], (lB_) + 32*64 + slot0);  DSR(bf_[2][1], (lB_) + 32*64 + slot1); \
    DSR(bf_[3][0], (lB_) + 48*64 + slot0);  DSR(bf_[3][1], (lB_) + 48*64 + slot1);

  #define MFMA16(jp_)                                                          \
    _Pragma("unroll")                                                          \
    for (int ni=0; ni<4; ++ni) {                                               \
      acc[2*(jp_)  ][ni] = __builtin_amdgcn_mfma_f32_16x16x32_bf16(aR[0], bf_[ni][0], acc[2*(jp_)  ][ni], 0,0,0); \
      acc[2*(jp_)  ][ni] = __builtin_amdgcn_mfma_f32_16x16x32_bf16(aR[1], bf_[ni][1], acc[2*(jp_)  ][ni], 0,0,0); \
      acc[2*(jp_)+1][ni] = __builtin_amdgcn_mfma_f32_16x16x32_bf16(aR[2], bf_[ni][0], acc[2*(jp_)+1][ni], 0,0,0); \
      acc[2*(jp_)+1][ni] = __builtin_amdgcn_mfma_f32_16x16x32_bf16(aR[3], bf_[ni][1], acc[2*(jp_)+1][ni], 0,0,0); \
    }

  #define LGKM0 do { asm volatile("s_waitcnt lgkmcnt(0)" ::: "memory");        \
                     __builtin_amdgcn_sched_barrier(0); } while(0)
  #define BAR   __builtin_amdgcn_s_barrier()
  #define VM4   asm volatile("s_waitcnt vmcnt(4)" ::: "memory")
  #define SETP1 __builtin_amdgcn_s_setprio(1)
  #define SETP0 __builtin_amdgcn_s_setprio(0)

  const int NITER = NT >> 1;
  for (int i = 0; i < NITER; ++i) {
    const int bt = 2*i + 1;
    const int a2 = (2*i+2 < NT) ? 2*i+2 : NT-1;
    const int b2 = (2*i+3 < NT) ? 2*i+3 : NT-1;

    READ_B8(lB0); READ_A4(lA0, 0);
    STG(0,0,bt,1, A, m0); STG(0,1,bt,1, A, m0);
    BAR; LGKM0;
    SETP1; MFMA16(0); SETP0;
    BAR;

    READ_A4(lA0, 1);
    STG(1,0,a2,0, Bt, n0); STG(1,1,a2,0, Bt, n0);
    BAR; LGKM0;
    SETP1; MFMA16(1); SETP0;
    VM4; BAR;

    READ_B8(lB1); READ_A4(lA1, 0);
    STG(0,0,a2,0, A, m0); STG(0,1,a2,0, A, m0);
    BAR; LGKM0;
    SETP1; MFMA16(0); SETP0;
    BAR;

    READ_A4(lA1, 1);
    STG(1,0,b2,1, Bt, n0); STG(1,1,b2,1, Bt, n0);
    BAR; LGKM0;
    SETP1; MFMA16(1); SETP0;
    VM4; BAR;
  }
  #undef STG
  #undef READ_A4
  #undef READ_B8
  #undef MFMA16
  #undef DSR
  #undef VM4

  // ---- epilogue: restage C (f32, bias added) through LDS ----
  asm volatile("s_waitcnt vmcnt(0)" ::: "memory");
  BAR;
  float* lsf = (float*)lds;                        // 128x128 f32 = 64 KiB
  #pragma unroll
  for (int ni=0;ni<4;ni++){
    const int col = wc*64 + ni*16 + lr;
    const float bc = bias[n0 + col];
    #pragma unroll
    for (int mi=0;mi<4;mi++){
      const int row0 = wr*64 + mi*16 + (lane>>4)*4;
      #pragma unroll
      for (int r=0;r<4;r++)
        lsf[(row0+r)*128 + col] = acc[mi][ni][r] + bc;
    }
  }
  asm volatile("s_waitcnt lgkmcnt(0)" ::: "memory");
  BAR;
  if constexpr (OUTK == 3) {
    u8* C = (u8*)Cout;
    #pragma unroll
    for (int it=0; it<16; ++it){
      const int c = t + 256*it;
      const int row = c >> 5, col4 = (c & 31) << 2;
      f32x4 v = *(const f32x4*)(lsf + ((size_t)c << 2));
      *(uint32_t*)(&C[(size_t)(m0 + row)*N + n0 + col4]) = enc4(v);
    }
  } else {
    float* C = (float*)Cout;
    #pragma unroll
    for (int it=0; it<16; ++it){
      const int c = t + 256*it;
      const int row = c >> 5, col4 = (c & 31) << 2;
      f32x4 v = *(const f32x4*)(lsf + ((size_t)c << 2));
      if constexpr (OUTK == 2) {
        const f32x4 rv = *(const f32x4*)(&res[(size_t)(m0 + row)*N + n0 + col4]);
        v = v + rv;
      }
      *(f32x4*)(&C[(size_t)(m0 + row)*N + n0 + col4]) = v;
    }
  }
  #undef BAR
  #undef LGKM0
  #undef SETP1
  #undef SETP0
}

// dual GEMM: blocks 0..2015 = value (fp8 out), 2016..2143 = offattn (f32 out)
__global__ __launch_bounds__(256, 2) void gemm_dual(
    const u16* __restrict__ A0, const u16* __restrict__ B0,
    const float* __restrict__ bias0, void* __restrict__ C0,
    const u16* __restrict__ A1, const u16* __restrict__ B1,
    const float* __restrict__ bias1, void* __restrict__ C1)
{
  __shared__ u16 lds[2][2][128*64];
  const int bid = blockIdx.x;
  if (bid < 2016)
    gemm_body<3>(A0, B0, bias0, nullptr, C0, 768, 768, 6, bid, 2016, lds);
  else
    gemm_body<1>(A1, B1, bias1, nullptr, C1, 256, 768, 2, bid - 2016, 128, lds);
}

// residual GEMM (out-projection)
__global__ __launch_bounds__(256, 2) void gemm_res(
    const u16* __restrict__ A, const u16* __restrict__ Bt,
    const float* __restrict__ bias, const float* __restrict__ res,
    void* __restrict__ Cout, int N, int K, int nbx)
{
  __shared__ u16 lds[2][2][128*64];
  gemm_body<2>(A, Bt, bias, res, Cout, N, K, nbx, blockIdx.x, gridDim.x, lds);
}

// ---------------- deformable sampling + attention-weighted accumulate ------
// R9 shape (proven best): 192 thr = 2 queries x 96 threads, 8 B gathers,
// grouped-4 gather batching.
#define NQ_ 4096
#define LV_ 21504

__global__ __launch_bounds__(192) void sample_kernel(
    const float* __restrict__ offattn, const float* __restrict__ refp,
    const u8* __restrict__ value, u16* __restrict__ accb)
{
  __shared__ float s_w[2][4][72];
  __shared__ int   s_idx[2][4][72];
  __shared__ float s_at[2][72];
  const int t = threadIdx.x;

  if (t < 144) {
    const int qi = t / 72, s = t % 72;
    const int bq = blockIdx.x*2 + qi;
    const float* row = offattn + (size_t)bq * 256;
    const int j = s % 12, l = j >> 2;
    const float Wf = (l==0) ? 128.f : ((l==1) ? 64.f : 32.f);
    const int   Wi = (l==0) ? 128   : ((l==1) ? 64   : 32);
    const int   st = (l==0) ? 0     : ((l==1) ? 16384 : 20480);
    const float rx = refp[((size_t)bq*3 + l)*2 + 0];
    const float ry = refp[((size_t)bq*3 + l)*2 + 1];
    const float px = rx*Wf + row[2*s]   - 0.5f;
    const float py = ry*Wf + row[2*s+1] - 0.5f;
    const float x0f = floorf(px), y0f = floorf(py);
    const int x0 = (int)x0f, y0 = (int)y0f;
    const float fx = px - x0f, fy = py - y0f;
    #pragma unroll
    for (int c=0;c<4;c++){
      const int dx = c & 1, dy = c >> 1;
      const int ix = x0 + dx, iy = y0 + dy;
      const float wgt = (dx ? fx : 1.f-fx) * (dy ? fy : 1.f-fy);
      const bool ok = (ix >= 0) && (ix < Wi) && (iy >= 0) && (iy < Wi);
      const int cx = min(max(ix,0),Wi-1), cy = min(max(iy,0),Wi-1);
      s_w[qi][c][s]   = ok ? wgt : 0.f;
      s_idx[qi][c][s] = st + cy*Wi + cx;
    }
  } else if (t < 156) {
    const int u = t - 144, qi = u / 6, h = u % 6;
    const int bq = blockIdx.x*2 + qi;
    const float* lg = offattn + (size_t)bq * 256 + 144 + h*12;
    float m = lg[0];
    #pragma unroll
    for (int j2=1;j2<12;j2++) m = fmaxf(m, lg[j2]);
    float e[12]; float sum = 0.f;
    #pragma unroll
    for (int j2=0;j2<12;j2++){ e[j2] = __expf(lg[j2]-m); sum += e[j2]; }
    const float inv = 1.f/sum;
    #pragma unroll
    for (int j2=0;j2<12;j2++) s_at[qi][h*12+j2] = e[j2]*inv;
  }
  __syncthreads();

  const int qi = t / 96, tt = t % 96;
  const int bq = blockIdx.x*2 + qi;
  const int b = bq >> 12;
  const int cb = tt * 8;          // fp8 column base (byte index)
  const int h = cb >> 7;          // head (128 cols/head)
  const u8* vb = value + (size_t)b * LV_ * 768;

  float ax[8];
  #pragma unroll
  for (int k=0;k<8;k++) ax[k] = 0.f;

  #pragma unroll
  for (int g=0; g<3; ++g){
    u32x2 uu[4][4];
    #pragma unroll
    for (int jj=0;jj<4;jj++){
      const int s = h*12 + g*4 + jj;
      #pragma unroll
      for (int c=0;c<4;c++)
        uu[jj][c] = *(const u32x2*)(vb + (size_t)s_idx[qi][c][s]*768 + cb);
    }
    #pragma unroll
    for (int jj=0;jj<4;jj++){
      const int s = h*12 + g*4 + jj;
      const float at = s_at[qi][s];
      float sx[8];
      #pragma unroll
      for (int k=0;k<8;k++) sx[k] = 0.f;
      #pragma unroll
      for (int c=0;c<4;c++){
        const float wgt = s_w[qi][c][s];
        float v[8];
        dec8(uu[jj][c], v);
        #pragma unroll
        for (int k=0;k<8;k++) sx[k] += wgt * v[k];
      }
      #pragma unroll
      for (int k=0;k<8;k++) ax[k] += at * sx[k];
    }
  }

  u16* ob = accb + (size_t)bq * 768 + cb;
  u32x4 o;
  #pragma unroll
  for (int k=0;k<4;k++)
    o[k] = ((uint32_t)f2bf(ax[2*k+1]) << 16) | (uint32_t)f2bf(ax[2*k]);
  *(u32x4*)ob = o;
}

// ---------------------------------------------------------------------------
extern "C" void kernel_launch(void* const* d_in, const int* in_sizes, int n_in,
                              void* d_out, int out_size, void* d_ws, size_t ws_size,
                              hipStream_t stream) {
  (void)in_sizes; (void)n_in; (void)out_size; (void)ws_size;
  const float* query = (const float*)d_in[0];
  const float* refp  = (const float*)d_in[1];
  const float* feat  = (const float*)d_in[2];
  const float* qn_g  = (const float*)d_in[3];
  const float* qn_b  = (const float*)d_in[4];
  const float* fn_g  = (const float*)d_in[5];
  const float* fn_b  = (const float*)d_in[6];
  const float* Wv    = (const float*)d_in[7];
  const float* bv    = (const float*)d_in[8];
  const float* Ws    = (const float*)d_in[9];
  const float* bs    = (const float*)d_in[10];
  const float* Wa    = (const float*)d_in[11];
  const float* ba    = (const float*)d_in[12];
  const float* Wo    = (const float*)d_in[13];
  const float* bo    = (const float*)d_in[14];
  float* out = (float*)d_out;

  constexpr size_t SZ_FLN  = (size_t)43008*768*2;
  constexpr size_t SZ_QLN  = (size_t)8192*768*2;
  constexpr size_t SZ_W    = (size_t)768*768*2;
  constexpr size_t SZ_WSAT = (size_t)256*768*2;
  char* ws = (char*)d_ws;
  u16*  fln   = (u16*)(ws);
  u8*   value = (u8*)(ws + SZ_FLN);               // fp8 (33 MB in 66 MB slot)
  u16*  qln   = (u16*)(ws + 2*SZ_FLN);
  u16*  Wvt   = (u16*)(ws + 2*SZ_FLN + SZ_QLN);
  u16*  Wot   = (u16*)(ws + 2*SZ_FLN + SZ_QLN + SZ_W);
  u16*  Wsat  = (u16*)(ws + 2*SZ_FLN + SZ_QLN + 2*SZ_W);
  float* bsa  = (float*)(ws + 2*SZ_FLN + SZ_QLN + 2*SZ_W + SZ_WSAT);
  float* offattn = (float*)fln;
  u16*   accb    = qln;

  // 1) fused LN + weight prep -- one dispatch (4096 LN blocks + 1465 prep)
  ln_prep<<<NLN + 1465, 256, 0, stream>>>(query, feat, qn_g, qn_b, fn_g, fn_b,
                                          qln, fln, Wv, Wo, Ws, Wa, bs, ba,
                                          Wvt, Wot, Wsat, bsa);

  // 2) fused value GEMM (fp8 out) + offattn GEMM (f32 out) -- one dispatch
  gemm_dual<<<2144, 256, 0, stream>>>(fln, Wvt, bv, value,
                                      qln, Wsat, bsa, offattn);

  // 3) deformable sampling (fp8 value) -> bf16 [8192, 768]
  sample_kernel<<<4096, 192, 0, stream>>>(offattn, refp, value, accb);

  // 4) out = acc @ Wo + bo + query -> f32  (64x6 = 384 blocks)
  gemm_res<<<384, 256, 0, stream>>>(accb, Wot, bo, query, out, 768, 768, 6);
}